// Round 10
// baseline (212.100 us; speedup 1.0000x reference)
//
#include <hip/hip_runtime.h>
#include <hip/hip_bf16.h>

// B=2, N=2048, E=1024, H=16, HD=64. Inputs fp32, output fp32.
// ws (32 MiB): kbuf qbuf vbuf sabuf (bf16, 8 MB each).
// Wqkv_t (6 MB) in sabuf region until attn; Wout_t (2 MB) in kbuf after attn.
// d_out (16 MB) as scratch: xbf = first 8 MB (until qkv done),
// vtb (V transposed [bh][d][n]) = second 8 MB (until out_mfma).
#define Bz 2
#define Nn 2048
#define Ee 1024
#define Hh 16
#define HD 64

typedef unsigned short u16;
typedef unsigned int u32;

typedef __bf16 bf16x8 __attribute__((ext_vector_type(8)));
typedef float f32x4 __attribute__((ext_vector_type(4)));

__device__ __forceinline__ float bf2f(u16 u) {
    u32 v = ((u32)u) << 16;
    return __builtin_bit_cast(float, v);
}
__device__ __forceinline__ u16 f2bf(float f) {
    u32 i = __builtin_bit_cast(u32, f);
    u32 r = (i + 0x7FFFu + ((i >> 16) & 1u)) >> 16;  // RNE
    return (u16)r;
}
__device__ __forceinline__ u32 pack2(float a, float b) {
    return (u32)f2bf(a) | ((u32)f2bf(b) << 16);
}
__device__ __forceinline__ bf16x8 ld_frag(const u16* p) {
    return __builtin_bit_cast(bf16x8, *(const uint4*)p);
}
__device__ __forceinline__ f32x4 zero4() {
    f32x4 z; z[0]=0.f; z[1]=0.f; z[2]=0.f; z[3]=0.f; return z;
}

// async 16B/lane global->LDS DMA; LDS dest = (uniform base) + lane*16.
__device__ __forceinline__ void async_copy16(const u16* g, u16* l) {
    __builtin_amdgcn_global_load_lds(
        (const __attribute__((address_space(1))) u32*)g,
        (__attribute__((address_space(3))) u32*)l, 16, 0, 0);
}

__global__ void ws_diag(float* out, float code) { out[0] = code; }

// ---------------------------------------------------------------------------
// x fp32 [4096*1024] -> bf16 row-major, into d_out scratch (first half).
// ---------------------------------------------------------------------------
__global__ __launch_bounds__(256) void convert_x(
    const float* __restrict__ x, u16* __restrict__ xbf)
{
    size_t idx = ((size_t)blockIdx.x * 256 + threadIdx.x) * 8;
    float4 f0 = *(const float4*)(x + idx);
    float4 f1 = *(const float4*)(x + idx + 4);
    uint4 pk;
    pk.x = pack2(f0.x, f0.y); pk.y = pack2(f0.z, f0.w);
    pk.z = pack2(f1.x, f1.y); pk.w = pack2(f1.z, f1.w);
    *(uint4*)(xbf + idx) = pk;
}

// ---------------------------------------------------------------------------
// Transpose f32 [R][C] -> bf16 [C][R], per z-slice. R,C multiples of 64.
// ---------------------------------------------------------------------------
__global__ __launch_bounds__(256) void transpose_f32_bf16(
    const float* __restrict__ src, u16* __restrict__ dst, int R, int C)
{
    const int r0 = blockIdx.x * 64, c0 = blockIdx.y * 64;
    const size_t zoff = (size_t)blockIdx.z * R * C;
    src += zoff; dst += zoff;
    const int tid = threadIdx.x;

    __shared__ float T[64][65];
    {
        int tr = tid >> 2, tc = (tid & 3) * 16;
        const float* s = src + (size_t)(r0 + tr) * C + c0 + tc;
#pragma unroll
        for (int j = 0; j < 4; ++j) {
            float4 v = ((const float4*)s)[j];
            T[tr][tc + 4 * j + 0] = v.x; T[tr][tc + 4 * j + 1] = v.y;
            T[tr][tc + 4 * j + 2] = v.z; T[tr][tc + 4 * j + 3] = v.w;
        }
    }
    __syncthreads();
    {
        int cc = tid >> 2, rr = (tid & 3) * 16;
        u16* d = dst + (size_t)(c0 + cc) * R + r0 + rr;
        u32 w[8];
#pragma unroll
        for (int i = 0; i < 8; ++i)
            w[i] = pack2(T[rr + 2 * i][cc], T[rr + 2 * i + 1][cc]);
        *(uint4*)(d)     = make_uint4(w[0], w[1], w[2], w[3]);
        *(uint4*)(d + 8) = make_uint4(w[4], w[5], w[6], w[7]);
    }
}

// ---------------------------------------------------------------------------
// Transpose bf16 [2048 n][64 d] -> [64 d][2048 n] per bh slice (V -> V^T).
// ---------------------------------------------------------------------------
__global__ __launch_bounds__(256) void transpose_v(
    const u16* __restrict__ src, u16* __restrict__ dst)
{
    const int n0 = blockIdx.x * 64;
    const size_t z = blockIdx.y;
    src += z * (size_t)Nn * HD;
    dst += z * (size_t)HD * Nn;
    const int tid = threadIdx.x;

    __shared__ u16 T[64][66];
    {
        int tr = tid >> 2, tc = (tid & 3) * 16;
        const u16* s = src + (size_t)(n0 + tr) * HD + tc;
        *(uint4*)&T[tr][tc]     = *(const uint4*)(s);
        *(uint4*)&T[tr][tc + 8] = *(const uint4*)(s + 8);
    }
    __syncthreads();
    {
        int cc = tid >> 2, rr = (tid & 3) * 16;
        u32 w[8];
#pragma unroll
        for (int i = 0; i < 8; ++i)
            w[i] = (u32)T[rr + 2 * i][cc] | ((u32)T[rr + 2 * i + 1][cc] << 16);
        u16* d = dst + (size_t)cc * Nn + n0 + rr;
        *(uint4*)(d)     = make_uint4(w[0], w[1], w[2], w[3]);
        *(uint4*)(d + 8) = make_uint4(w[4], w[5], w[6], w[7]);
    }
}

// ---------------------------------------------------------------------------
// Kernel 1: QKV projection, MFMA 16x16x32, async staging (unchanged R8).
// ---------------------------------------------------------------------------
__global__ __launch_bounds__(256) void qkv_mfma(
    const u16* __restrict__ xbf, const u16* __restrict__ Wt,
    const float* __restrict__ bias,
    u16* __restrict__ kbuf, u16* __restrict__ qbuf, u16* __restrict__ vbuf)
{
    const int mt = blockIdx.x;   // 0..63
    const int h  = blockIdx.y;   // 0..15
    const int tid = threadIdx.x;
    const int lane = tid & 63, wid = tid >> 6;
    const int quad = lane >> 4, l15 = lane & 15;

    __shared__ u16 As[64 * 64];
    __shared__ u16 Bs[192 * 64];

    f32x4 acc[4][3];
#pragma unroll
    for (int mi = 0; mi < 4; ++mi)
#pragma unroll
        for (int ni = 0; ni < 3; ++ni) acc[mi][ni] = zero4();

    const u16* xb = xbf + (size_t)mt * 64 * Ee;
    const u16* wtb = Wt + (size_t)h * 192 * 1024;

    const int arowl = lane >> 3;
    const int jj = (lane & 7) ^ arowl;

    for (int kb = 0; kb < 16; ++kb) {
        __syncthreads();
#pragma unroll
        for (int i = 0; i < 2; ++i) {
            int rbase = (wid * 2 + i) * 8;
            const u16* g = xb + (size_t)(rbase + arowl) * Ee + kb * 64 + jj * 8;
            async_copy16(g, &As[(wid * 2 + i) * 512]);
        }
#pragma unroll
        for (int i = 0; i < 6; ++i) {
            int rbase = (wid * 6 + i) * 8;
            const u16* g = wtb + (size_t)(rbase + arowl) * 1024 + kb * 64 + jj * 8;
            async_copy16(g, &Bs[(wid * 6 + i) * 512]);
        }
        __syncthreads();

#pragma unroll
        for (int kk0 = 0; kk0 < 2; ++kk0) {
            const int pos = ((kk0 * 4 + quad) ^ (l15 & 7)) * 8;
            bf16x8 af[4], bf[3];
#pragma unroll
            for (int mi = 0; mi < 4; ++mi)
                af[mi] = ld_frag(&As[(mi * 16 + l15) * 64 + pos]);
#pragma unroll
            for (int ni = 0; ni < 3; ++ni)
                bf[ni] = ld_frag(&Bs[(wid * 48 + ni * 16 + l15) * 64 + pos]);
#pragma unroll
            for (int mi = 0; mi < 4; ++mi)
#pragma unroll
                for (int ni = 0; ni < 3; ++ni)
                    acc[mi][ni] = __builtin_amdgcn_mfma_f32_16x16x32_bf16(
                        af[mi], bf[ni], acc[mi][ni], 0, 0, 0);
        }
    }

#pragma unroll
    for (int ni = 0; ni < 3; ++ni) {
        int col = wid * 48 + ni * 16 + l15;   // 0..191
        int ft = col >> 6, d = col & 63;
        u16* dst = (ft == 0) ? kbuf : (ft == 1) ? qbuf : vbuf;
        float bv = bias[h * 192 + col];
#pragma unroll
        for (int mi = 0; mi < 4; ++mi)
#pragma unroll
            for (int r = 0; r < 4; ++r) {
                int gm = mt * 64 + mi * 16 + quad * 4 + r;
                int bb = gm >> 11, n = gm & (Nn - 1);
                dst[(((size_t)(bb * Hh + h)) * Nn + n) * HD + d] =
                    f2bf(acc[mi][ni][r] + bv);
            }
    }
}

// ---------------------------------------------------------------------------
// Kernel 2 v4: causal flash attention, transposed-S, MFMA 16x16x32.
// 128-thread blocks (2 waves), q-tile 32, pairs (p, 63-p) -> uniform 33
// iters; grid 1024 = 4 blocks/CU (16 waves/CU). XCD-aware bh grouping so
// one XCD's L2 serves 4 bh. Double-buffered async K/V^T staging. Exactly
// one masked (diagonal) iter per q-tile; all others mask-free.
// ---------------------------------------------------------------------------
__global__ __launch_bounds__(128) void attn2(
    const u16* __restrict__ qbuf, const u16* __restrict__ kbuf,
    const u16* __restrict__ vtb, u16* __restrict__ sabuf)
{
    const int id = blockIdx.x;               // 0..1023
    const int bh = (id & 7) * 4 + ((id >> 3) & 3);  // XCD-grouped
    const int p  = id >> 5;                  // 0..31 (pair index, q-tile32)
    const int b = bh >> 4, h = bh & 15;
    const int tid = threadIdx.x;
    const int lane = tid & 63, wid = tid >> 6;  // wid 0..1
    const int l15 = lane & 15, quad = lane >> 4;

    __shared__ u16 KsL[2][4096];   // [buf][key 64][d 64] chunk-swizzled
    __shared__ u16 VtL[2][4096];   // [buf][d 64][key 64] chunk-swizzled

    const u16* qb = qbuf + (size_t)bh * Nn * HD;
    const u16* kb = kbuf + (size_t)bh * Nn * HD;
    const u16* vt = vtb + (size_t)bh * HD * Nn;   // [d][n]

    const int r_l = lane >> 3;
    const int jj = (lane & 7) ^ r_l;
    const int xsw = l15 & 7;

    const int src0 = l15 + (quad & 1) * 32;
    const bool qhi = quad >= 2;

    const float SC = 0.18033688f;  // 0.125 * log2(e)

    for (int hx = 0; hx < 2; ++hx) {
        const int qt = hx ? (63 - p) : p;     // q-tile32 index 0..63
        const int nkt = (qt + 2) >> 1;        // 64-key tiles
        const int qrow = qt * 32 + wid * 16 + l15;

        bf16x8 qf[2];
#pragma unroll
        for (int st = 0; st < 2; ++st)
            qf[st] = __builtin_bit_cast(bf16x8,
                *(const uint4*)(qb + (size_t)qrow * HD + st * 32 + quad * 8));

        f32x4 oacc[4];
#pragma unroll
        for (int dt = 0; dt < 4; ++dt) oacc[dt] = zero4();
        float m_i = -3e38f, l_i = 0.f;

        // prologue: stage tile 0 into buf 0. wave0 -> K, wave1 -> V^T.
        __syncthreads();
#pragma unroll
        for (int i = 0; i < 8; ++i) {
            if (wid == 0) {
                const u16* g = kb + (size_t)(i * 8 + r_l) * HD + jj * 8;
                async_copy16(g, &KsL[0][i * 512]);
            } else {
                const u16* g = vt + (size_t)(i * 8 + r_l) * Nn + jj * 8;
                async_copy16(g, &VtL[0][i * 512]);
            }
        }

        for (int kt = 0; kt < nkt; ++kt) {
            __syncthreads();  // drains DMA for buf[kt&1]; fences prev reads
            if (kt + 1 < nkt) {
                const int nb = (kt + 1) & 1;
#pragma unroll
                for (int i = 0; i < 8; ++i) {
                    if (wid == 0) {
                        const u16* g = kb + (size_t)((kt + 1) * 64 + i * 8 + r_l) * HD + jj * 8;
                        async_copy16(g, &KsL[nb][i * 512]);
                    } else {
                        const u16* g = vt + (size_t)(i * 8 + r_l) * Nn + (kt + 1) * 64 + jj * 8;
                        async_copy16(g, &VtL[nb][i * 512]);
                    }
                }
            }
            const u16* K = KsL[kt & 1];
            const u16* V = VtL[kt & 1];

            // S^T[key][q]: 4 key-tiles of 16
            f32x4 s[4];
#pragma unroll
            for (int t = 0; t < 4; ++t) {
                f32x4 a = zero4();
#pragma unroll
                for (int st = 0; st < 2; ++st) {
                    bf16x8 kf = ld_frag(&K[(t * 16 + l15) * 64 +
                                           ((st * 4 + quad) ^ xsw) * 8]);
                    a = __builtin_amdgcn_mfma_f32_16x16x32_bf16(kf, qf[st], a, 0, 0, 0);
                }
                s[t] = a;
            }

            // scale (log2 domain); mask only on the single diagonal iter
            if (kt == nkt - 1) {
#pragma unroll
                for (int t = 0; t < 4; ++t)
#pragma unroll
                    for (int r = 0; r < 4; ++r) {
                        int key = kt * 64 + t * 16 + quad * 4 + r;
                        float v = s[t][r] * SC;
                        if (key > qrow) v = -3e38f;
                        s[t][r] = v;
                    }
            } else {
#pragma unroll
                for (int t = 0; t < 4; ++t)
#pragma unroll
                    for (int r = 0; r < 4; ++r) s[t][r] *= SC;
            }

            // online softmax: in-lane + 2 shuffles; exp2
            float mx = s[0][0];
#pragma unroll
            for (int t = 0; t < 4; ++t)
#pragma unroll
                for (int r = 0; r < 4; ++r) mx = fmaxf(mx, s[t][r]);
            mx = fmaxf(mx, __shfl_xor(mx, 16));
            mx = fmaxf(mx, __shfl_xor(mx, 32));
            float mn = fmaxf(m_i, mx);
            float alpha = exp2f(m_i - mn);
            m_i = mn;
            float rs = 0.f;
#pragma unroll
            for (int t = 0; t < 4; ++t)
#pragma unroll
                for (int r = 0; r < 4; ++r) {
                    float e = exp2f(s[t][r] - mn);
                    s[t][r] = e;
                    rs += e;
                }
            rs += __shfl_xor(rs, 16);
            rs += __shfl_xor(rs, 32);
            l_i = l_i * alpha + rs;
#pragma unroll
            for (int dt = 0; dt < 4; ++dt)
#pragma unroll
                for (int r = 0; r < 4; ++r) oacc[dt][r] *= alpha;

            // pack P; B-frags via both-candidate shuffle + dest-side select
            u32 pk[4][2];
#pragma unroll
            for (int t = 0; t < 4; ++t) {
                pk[t][0] = pack2(s[t][0], s[t][1]);
                pk[t][1] = pack2(s[t][2], s[t][3]);
            }
#pragma unroll
            for (int st = 0; st < 2; ++st) {
                u32 e0 = pk[2 * st][0],     e1 = pk[2 * st][1];
                u32 o0 = pk[2 * st + 1][0], o1 = pk[2 * st + 1][1];
                u32 A0 = __shfl(e0, src0),      B0 = __shfl(o0, src0);
                u32 A1 = __shfl(e1, src0),      B1 = __shfl(o1, src0);
                u32 A2 = __shfl(e0, src0 + 16), B2 = __shfl(o0, src0 + 16);
                u32 A3 = __shfl(e1, src0 + 16), B3 = __shfl(o1, src0 + 16);
                u32 U0 = qhi ? B0 : A0;
                u32 U1 = qhi ? B1 : A1;
                u32 U2 = qhi ? B2 : A2;
                u32 U3 = qhi ? B3 : A3;
                bf16x8 pf = __builtin_bit_cast(bf16x8, make_uint4(U0, U1, U2, U3));
#pragma unroll
                for (int dt = 0; dt < 4; ++dt) {
                    bf16x8 vf = ld_frag(&V[(dt * 16 + l15) * 64 +
                                           ((st * 4 + quad) ^ xsw) * 8]);
                    oacc[dt] = __builtin_amdgcn_mfma_f32_16x16x32_bf16(
                        vf, pf, oacc[dt], 0, 0, 0);
                }
            }
        }

        // epilogue: O^T C-layout col=q(lane), row=d(quad*4+r)
        float inv = 1.f / l_i;
#pragma unroll
        for (int dt = 0; dt < 4; ++dt) {
            ushort4 ov;
            ov.x = f2bf(oacc[dt][0] * inv);
            ov.y = f2bf(oacc[dt][1] * inv);
            ov.z = f2bf(oacc[dt][2] * inv);
            ov.w = f2bf(oacc[dt][3] * inv);
            *(ushort4*)&sabuf[((size_t)(b * Nn + qrow)) * Ee + h * 64 +
                              dt * 16 + quad * 4] = ov;
        }
    }
}

// ---------------------------------------------------------------------------
// Kernel 3: output projection, MFMA 32x32x16 (unchanged).
// ---------------------------------------------------------------------------
typedef float f32x16 __attribute__((ext_vector_type(16)));
__device__ __forceinline__ f32x16 zero16() {
    f32x16 z;
#pragma unroll
    for (int i = 0; i < 16; ++i) z[i] = 0.f;
    return z;
}

__global__ __launch_bounds__(256) void out_mfma(
    const u16* __restrict__ A, const u16* __restrict__ Wt,
    const float* __restrict__ bias, float* __restrict__ out)
{
    const int mt = blockIdx.x;  // 0..31
    const int nt = blockIdx.y;  // 0..15
    const int tid = threadIdx.x;
    const int lane = tid & 63, wid = tid >> 6;
    const int l31 = lane & 31, khalf = (lane >> 5) * 8;

    __shared__ u16 As[128][72];
    __shared__ u16 Bs[64][72];

    f32x16 acc[2];
    acc[0] = zero16(); acc[1] = zero16();

    const u16* ab = A + (size_t)mt * 128 * Ee;
    const int arow = tid >> 1, akh = (tid & 1) * 32;
    const int brow = tid >> 2, bc = (tid & 3) * 16;

    for (int k0 = 0; k0 < Ee; k0 += 64) {
        __syncthreads();
        {
            const u16* asrc = ab + (size_t)arow * Ee + k0 + akh;
#pragma unroll
            for (int j = 0; j < 4; ++j)
                *(uint4*)&As[arow][akh + 8 * j] = *(const uint4*)(asrc + 8 * j);
            const u16* bsrc = Wt + (size_t)(nt * 64 + brow) * 1024 + k0 + bc;
            *(uint4*)&Bs[brow][bc]     = *(const uint4*)(bsrc);
            *(uint4*)&Bs[brow][bc + 8] = *(const uint4*)(bsrc + 8);
        }
        __syncthreads();
#pragma unroll
        for (int kc = 0; kc < 4; ++kc) {
            bf16x8 af = ld_frag(&As[wid * 32 + l31][kc * 16 + khalf]);
#pragma unroll
            for (int ct = 0; ct < 2; ++ct) {
                bf16x8 bf = ld_frag(&Bs[ct * 32 + l31][kc * 16 + khalf]);
                acc[ct] = __builtin_amdgcn_mfma_f32_32x32x16_bf16(af, bf, acc[ct], 0, 0, 0);
            }
        }
    }

#pragma unroll
    for (int ct = 0; ct < 2; ++ct) {
        int col = nt * 64 + ct * 32 + l31;
        float bv = bias[col];
#pragma unroll
        for (int r = 0; r < 16; ++r) {
            int row_l = (r & 3) + 8 * (r >> 2) + 4 * (lane >> 5);
            int gm = mt * 128 + wid * 32 + row_l;
            out[(size_t)gm * Ee + col] = acc[ct][r] + bv;
        }
    }
}

// ---------------------------------------------------------------------------
extern "C" void kernel_launch(void* const* d_in, const int* in_sizes, int n_in,
                              void* d_out, int out_size, void* d_ws, size_t ws_size,
                              hipStream_t stream) {
    const float* x    = (const float*)d_in[0];  // [2,2048,1024] f32
    const float* Wqkv = (const float*)d_in[1];  // [16,1024,192] f32
    const float* bqkv = (const float*)d_in[2];  // [16,192] f32
    const float* Wout = (const float*)d_in[3];  // [1024,1024] f32
    const float* bout = (const float*)d_in[4];  // [1024] f32
    float* out = (float*)d_out;                 // [2,2048,1024] f32

    const size_t SZ = (size_t)Bz * Hh * Nn * HD;        // 4,194,304 elems
    const size_t NSA = (size_t)Bz * Nn * Ee;            // 4,194,304 elems
    const size_t NEED = (3 * SZ + NSA) * sizeof(u16);   // 32 MiB

    if (ws_size < NEED) {
        ws_diag<<<1, 1, 0, stream>>>(out, 20000.0f + (float)(ws_size >> 20));
        return;
    }

    u16* ws = (u16*)d_ws;
    u16* kbuf  = ws;
    u16* qbuf  = ws + SZ;
    u16* vbuf  = ws + 2 * SZ;
    u16* sabuf = ws + 3 * SZ;
    u16* wqkv_t = sabuf;             // 6 MB in dead sa region (until attn2)
    u16* wout_t = kbuf;              // 2 MB in dead k region (after attn2)
    u16* xbf    = (u16*)d_out;       // 8 MB scratch (until qkv done)
    u16* vtb    = (u16*)d_out + SZ;  // 8 MB scratch (until out_mfma)

    convert_x<<<2048, 256, 0, stream>>>(x, xbf);
    transpose_f32_bf16<<<dim3(16, 3, 16), 256, 0, stream>>>(Wqkv, wqkv_t, 1024, 192);
    qkv_mfma<<<dim3(64, 16), 256, 0, stream>>>(xbf, wqkv_t, bqkv, kbuf, qbuf, vbuf);
    transpose_v<<<dim3(32, 32), 256, 0, stream>>>(vbuf, vtb);
    attn2<<<dim3(1024), 128, 0, stream>>>(qbuf, kbuf, vtb, sabuf);
    transpose_f32_bf16<<<dim3(16, 16, 1), 256, 0, stream>>>(Wout, wout_t, 1024, 1024);
    out_mfma<<<dim3(32, 16), 256, 0, stream>>>(sabuf, wout_t, bout, out);
}

// Round 11
// 205.398 us; speedup vs baseline: 1.0326x; 1.0326x over previous
//
#include <hip/hip_runtime.h>
#include <hip/hip_bf16.h>

// B=2, N=2048, E=1024, H=16, HD=64. Inputs fp32, output fp32.
// ws (32 MiB): kbuf qbuf vbuf sabuf (bf16, 8 MB each).
// Scratch plan:
//   wqkv_t (6 MB)  -> sabuf region, dead after qkv_mfma
//   xbf    (8 MB)  -> d_out[0..8M),  dead after qkv_mfma
//   vtb    (8 MB)  -> d_out[8..16M), dead after attn2
//   p0     (8 MB)  -> d_out[0..8M)  (attn2 partial 0, dead after merge)
//   p1     (8 MB)  -> vbuf          (attn2 partial 1; merge overwrites in place
//                                    with final sa, elementwise -> race-free)
//   m/l    (1 MB)  -> sabuf head (4 x 64K f32), dead after merge
//   wout_t (2 MB)  -> kbuf, written after attn2 (kbuf dead then)
#define Bz 2
#define Nn 2048
#define Ee 1024
#define Hh 16
#define HD 64

typedef unsigned short u16;
typedef unsigned int u32;

typedef __bf16 bf16x8 __attribute__((ext_vector_type(8)));
typedef float f32x4 __attribute__((ext_vector_type(4)));

__device__ __forceinline__ float bf2f(u16 u) {
    u32 v = ((u32)u) << 16;
    return __builtin_bit_cast(float, v);
}
__device__ __forceinline__ u16 f2bf(float f) {
    u32 i = __builtin_bit_cast(u32, f);
    u32 r = (i + 0x7FFFu + ((i >> 16) & 1u)) >> 16;  // RNE
    return (u16)r;
}
__device__ __forceinline__ u32 pack2(float a, float b) {
    return (u32)f2bf(a) | ((u32)f2bf(b) << 16);
}
__device__ __forceinline__ bf16x8 ld_frag(const u16* p) {
    return __builtin_bit_cast(bf16x8, *(const uint4*)p);
}
__device__ __forceinline__ f32x4 zero4() {
    f32x4 z; z[0]=0.f; z[1]=0.f; z[2]=0.f; z[3]=0.f; return z;
}

// async 16B/lane global->LDS DMA; LDS dest = (uniform base) + lane*16.
__device__ __forceinline__ void async_copy16(const u16* g, u16* l) {
    __builtin_amdgcn_global_load_lds(
        (const __attribute__((address_space(1))) u32*)g,
        (__attribute__((address_space(3))) u32*)l, 16, 0, 0);
}

__global__ void ws_diag(float* out, float code) { out[0] = code; }

// ---------------------------------------------------------------------------
// x fp32 -> bf16 row-major into d_out scratch (first half).
// ---------------------------------------------------------------------------
__global__ __launch_bounds__(256) void convert_x(
    const float* __restrict__ x, u16* __restrict__ xbf)
{
    size_t idx = ((size_t)blockIdx.x * 256 + threadIdx.x) * 8;
    float4 f0 = *(const float4*)(x + idx);
    float4 f1 = *(const float4*)(x + idx + 4);
    uint4 pk;
    pk.x = pack2(f0.x, f0.y); pk.y = pack2(f0.z, f0.w);
    pk.z = pack2(f1.x, f1.y); pk.w = pack2(f1.z, f1.w);
    *(uint4*)(xbf + idx) = pk;
}

// ---------------------------------------------------------------------------
// Transpose f32 [R][C] -> bf16 [C][R], per z-slice.
// ---------------------------------------------------------------------------
__global__ __launch_bounds__(256) void transpose_f32_bf16(
    const float* __restrict__ src, u16* __restrict__ dst, int R, int C)
{
    const int r0 = blockIdx.x * 64, c0 = blockIdx.y * 64;
    const size_t zoff = (size_t)blockIdx.z * R * C;
    src += zoff; dst += zoff;
    const int tid = threadIdx.x;

    __shared__ float T[64][65];
    {
        int tr = tid >> 2, tc = (tid & 3) * 16;
        const float* s = src + (size_t)(r0 + tr) * C + c0 + tc;
#pragma unroll
        for (int j = 0; j < 4; ++j) {
            float4 v = ((const float4*)s)[j];
            T[tr][tc + 4 * j + 0] = v.x; T[tr][tc + 4 * j + 1] = v.y;
            T[tr][tc + 4 * j + 2] = v.z; T[tr][tc + 4 * j + 3] = v.w;
        }
    }
    __syncthreads();
    {
        int cc = tid >> 2, rr = (tid & 3) * 16;
        u16* d = dst + (size_t)(c0 + cc) * R + r0 + rr;
        u32 w[8];
#pragma unroll
        for (int i = 0; i < 8; ++i)
            w[i] = pack2(T[rr + 2 * i][cc], T[rr + 2 * i + 1][cc]);
        *(uint4*)(d)     = make_uint4(w[0], w[1], w[2], w[3]);
        *(uint4*)(d + 8) = make_uint4(w[4], w[5], w[6], w[7]);
    }
}

// ---------------------------------------------------------------------------
// Transpose bf16 [2048 n][64 d] -> [64 d][2048 n] per bh slice (V -> V^T).
// ---------------------------------------------------------------------------
__global__ __launch_bounds__(256) void transpose_v(
    const u16* __restrict__ src, u16* __restrict__ dst)
{
    const int n0 = blockIdx.x * 64;
    const size_t z = blockIdx.y;
    src += z * (size_t)Nn * HD;
    dst += z * (size_t)HD * Nn;
    const int tid = threadIdx.x;

    __shared__ u16 T[64][66];
    {
        int tr = tid >> 2, tc = (tid & 3) * 16;
        const u16* s = src + (size_t)(n0 + tr) * HD + tc;
        *(uint4*)&T[tr][tc]     = *(const uint4*)(s);
        *(uint4*)&T[tr][tc + 8] = *(const uint4*)(s + 8);
    }
    __syncthreads();
    {
        int cc = tid >> 2, rr = (tid & 3) * 16;
        u32 w[8];
#pragma unroll
        for (int i = 0; i < 8; ++i)
            w[i] = (u32)T[rr + 2 * i][cc] | ((u32)T[rr + 2 * i + 1][cc] << 16);
        u16* d = dst + (size_t)cc * Nn + n0 + rr;
        *(uint4*)(d)     = make_uint4(w[0], w[1], w[2], w[3]);
        *(uint4*)(d + 8) = make_uint4(w[4], w[5], w[6], w[7]);
    }
}

// ---------------------------------------------------------------------------
// Kernel 1: QKV projection, MFMA 16x16x32, async staging (unchanged R8).
// ---------------------------------------------------------------------------
__global__ __launch_bounds__(256) void qkv_mfma(
    const u16* __restrict__ xbf, const u16* __restrict__ Wt,
    const float* __restrict__ bias,
    u16* __restrict__ kbuf, u16* __restrict__ qbuf, u16* __restrict__ vbuf)
{
    const int mt = blockIdx.x;   // 0..63
    const int h  = blockIdx.y;   // 0..15
    const int tid = threadIdx.x;
    const int lane = tid & 63, wid = tid >> 6;
    const int quad = lane >> 4, l15 = lane & 15;

    __shared__ u16 As[64 * 64];
    __shared__ u16 Bs[192 * 64];

    f32x4 acc[4][3];
#pragma unroll
    for (int mi = 0; mi < 4; ++mi)
#pragma unroll
        for (int ni = 0; ni < 3; ++ni) acc[mi][ni] = zero4();

    const u16* xb = xbf + (size_t)mt * 64 * Ee;
    const u16* wtb = Wt + (size_t)h * 192 * 1024;

    const int arowl = lane >> 3;
    const int jj = (lane & 7) ^ arowl;

    for (int kb = 0; kb < 16; ++kb) {
        __syncthreads();
#pragma unroll
        for (int i = 0; i < 2; ++i) {
            int rbase = (wid * 2 + i) * 8;
            const u16* g = xb + (size_t)(rbase + arowl) * Ee + kb * 64 + jj * 8;
            async_copy16(g, &As[(wid * 2 + i) * 512]);
        }
#pragma unroll
        for (int i = 0; i < 6; ++i) {
            int rbase = (wid * 6 + i) * 8;
            const u16* g = wtb + (size_t)(rbase + arowl) * 1024 + kb * 64 + jj * 8;
            async_copy16(g, &Bs[(wid * 6 + i) * 512]);
        }
        __syncthreads();

#pragma unroll
        for (int kk0 = 0; kk0 < 2; ++kk0) {
            const int pos = ((kk0 * 4 + quad) ^ (l15 & 7)) * 8;
            bf16x8 af[4], bf[3];
#pragma unroll
            for (int mi = 0; mi < 4; ++mi)
                af[mi] = ld_frag(&As[(mi * 16 + l15) * 64 + pos]);
#pragma unroll
            for (int ni = 0; ni < 3; ++ni)
                bf[ni] = ld_frag(&Bs[(wid * 48 + ni * 16 + l15) * 64 + pos]);
#pragma unroll
            for (int mi = 0; mi < 4; ++mi)
#pragma unroll
                for (int ni = 0; ni < 3; ++ni)
                    acc[mi][ni] = __builtin_amdgcn_mfma_f32_16x16x32_bf16(
                        af[mi], bf[ni], acc[mi][ni], 0, 0, 0);
        }
    }

#pragma unroll
    for (int ni = 0; ni < 3; ++ni) {
        int col = wid * 48 + ni * 16 + l15;   // 0..191
        int ft = col >> 6, d = col & 63;
        u16* dst = (ft == 0) ? kbuf : (ft == 1) ? qbuf : vbuf;
        float bv = bias[h * 192 + col];
#pragma unroll
        for (int mi = 0; mi < 4; ++mi)
#pragma unroll
            for (int r = 0; r < 4; ++r) {
                int gm = mt * 64 + mi * 16 + quad * 4 + r;
                int bb = gm >> 11, n = gm & (Nn - 1);
                dst[(((size_t)(bb * Hh + h)) * Nn + n) * HD + d] =
                    f2bf(acc[mi][ni][r] + bv);
            }
    }
}

// ---------------------------------------------------------------------------
// Kernel 2 v5: split-K causal flash attention, transposed-S, MFMA 16x16x32.
// 256-thr blocks, q-tile 64. Each (bh, qt) is split: seg A = first ceil(T/2)
// key-tiles (block pair-index p=qt), seg B = last floor(T/2) (block 31-p).
// Each block does segA(qt=p) + segB(qt=31-p) -> uniform 16-17 iters.
// Grid 1024 = 4096 waves (2x R9) for latency hiding. XCD-grouped bh.
// Emits UNNORMALIZED partials O' (bf16) + m,l (f32); merged by attn_merge.
// ---------------------------------------------------------------------------
__global__ __launch_bounds__(256) void attn2(
    const u16* __restrict__ qbuf, const u16* __restrict__ kbuf,
    const u16* __restrict__ vtb, u16* __restrict__ p0buf,
    u16* __restrict__ p1buf, float* __restrict__ ml)
{
    const int id = blockIdx.x;                      // 0..1023
    const int bh = (id & 7) * 4 + ((id >> 3) & 3);  // 4 bh per XCD
    const int p  = id >> 5;                         // 0..31
    const int tid = threadIdx.x;
    const int lane = tid & 63, wid = tid >> 6;
    const int l15 = lane & 15, quad = lane >> 4;

    __shared__ u16 KsL[2][4096];   // [buf][key 64][d 64] chunk-swizzled
    __shared__ u16 VtL[2][4096];   // [buf][d 64][key 64] chunk-swizzled

    const u16* qb = qbuf + (size_t)bh * Nn * HD;
    const u16* kb = kbuf + (size_t)bh * Nn * HD;
    const u16* vt = vtb + (size_t)bh * HD * Nn;

    const int r_l = lane >> 3;
    const int jj = (lane & 7) ^ r_l;
    const int xsw = l15 & 7;
    const int src0 = l15 + (quad & 1) * 32;
    const bool qhi = quad >= 2;
    const float SC = 0.18033688f;  // 0.125 * log2(e)

    for (int sg = 0; sg < 2; ++sg) {
        const int qt = sg ? (31 - p) : p;
        const int T  = qt + 1;
        const int t0 = sg ? ((T + 1) >> 1) : 0;
        const int t1 = sg ? T : ((p + 2) >> 1);
        u16*   pb = sg ? p1buf : p0buf;
        float* mb = ml + (sg ? 131072 : 0);
        float* lb = ml + (sg ? 196608 : 65536);

        const int qrow = qt * 64 + wid * 16 + l15;

        f32x4 oacc[4];
#pragma unroll
        for (int dt = 0; dt < 4; ++dt) oacc[dt] = zero4();
        float m_i = -3e38f, l_i = 0.f;

        if (t0 < t1) {
            bf16x8 qf[2];
#pragma unroll
            for (int st = 0; st < 2; ++st)
                qf[st] = __builtin_bit_cast(bf16x8,
                    *(const uint4*)(qb + (size_t)qrow * HD + st * 32 + quad * 8));

            // prologue: stage tile t0 into buf 0
            __syncthreads();
#pragma unroll
            for (int i2 = 0; i2 < 4; ++i2) {
                int idx = wid * 4 + i2;
                if (idx < 8) {
                    const u16* g = kb + (size_t)(t0 * 64 + idx * 8 + r_l) * HD + jj * 8;
                    async_copy16(g, &KsL[0][idx * 512]);
                } else {
                    int ii = idx - 8;
                    const u16* g = vt + (size_t)(ii * 8 + r_l) * Nn + t0 * 64 + jj * 8;
                    async_copy16(g, &VtL[0][ii * 512]);
                }
            }

            const int nit = t1 - t0;
            for (int i = 0; i < nit; ++i) {
                const int tk = t0 + i;
                __syncthreads();  // drains DMA for buf[i&1]; fences prev reads
                if (i + 1 < nit) {
                    const int nb = (i + 1) & 1;
#pragma unroll
                    for (int i2 = 0; i2 < 4; ++i2) {
                        int idx = wid * 4 + i2;
                        if (idx < 8) {
                            const u16* g = kb + (size_t)((tk + 1) * 64 + idx * 8 + r_l) * HD + jj * 8;
                            async_copy16(g, &KsL[nb][idx * 512]);
                        } else {
                            int ii = idx - 8;
                            const u16* g = vt + (size_t)(ii * 8 + r_l) * Nn + (tk + 1) * 64 + jj * 8;
                            async_copy16(g, &VtL[nb][ii * 512]);
                        }
                    }
                }
                const u16* K = KsL[i & 1];
                const u16* V = VtL[i & 1];

                // S^T[key][q]: 4 key-tiles of 16
                f32x4 s[4];
#pragma unroll
                for (int t = 0; t < 4; ++t) {
                    f32x4 a = zero4();
#pragma unroll
                    for (int st = 0; st < 2; ++st) {
                        bf16x8 kf = ld_frag(&K[(t * 16 + l15) * 64 +
                                               ((st * 4 + quad) ^ xsw) * 8]);
                        a = __builtin_amdgcn_mfma_f32_16x16x32_bf16(kf, qf[st], a, 0, 0, 0);
                    }
                    s[t] = a;
                }

                // scale (log2 domain); mask only on the diagonal tile
                if (tk == qt) {
#pragma unroll
                    for (int t = 0; t < 4; ++t)
#pragma unroll
                        for (int r = 0; r < 4; ++r) {
                            int key = tk * 64 + t * 16 + quad * 4 + r;
                            float v = s[t][r] * SC;
                            if (key > qrow) v = -3e38f;
                            s[t][r] = v;
                        }
                } else {
#pragma unroll
                    for (int t = 0; t < 4; ++t)
#pragma unroll
                        for (int r = 0; r < 4; ++r) s[t][r] *= SC;
                }

                // online softmax: in-lane + 2 shuffles; exp2
                float mx = s[0][0];
#pragma unroll
                for (int t = 0; t < 4; ++t)
#pragma unroll
                    for (int r = 0; r < 4; ++r) mx = fmaxf(mx, s[t][r]);
                mx = fmaxf(mx, __shfl_xor(mx, 16));
                mx = fmaxf(mx, __shfl_xor(mx, 32));
                float mn = fmaxf(m_i, mx);
                float alpha = exp2f(m_i - mn);
                m_i = mn;
                float rs = 0.f;
#pragma unroll
                for (int t = 0; t < 4; ++t)
#pragma unroll
                    for (int r = 0; r < 4; ++r) {
                        float e = exp2f(s[t][r] - mn);
                        s[t][r] = e;
                        rs += e;
                    }
                rs += __shfl_xor(rs, 16);
                rs += __shfl_xor(rs, 32);
                l_i = l_i * alpha + rs;
#pragma unroll
                for (int dt = 0; dt < 4; ++dt)
#pragma unroll
                    for (int r = 0; r < 4; ++r) oacc[dt][r] *= alpha;

                // pack P; B-frags via both-candidate shuffle + dest-side select
                u32 pk[4][2];
#pragma unroll
                for (int t = 0; t < 4; ++t) {
                    pk[t][0] = pack2(s[t][0], s[t][1]);
                    pk[t][1] = pack2(s[t][2], s[t][3]);
                }
#pragma unroll
                for (int st = 0; st < 2; ++st) {
                    u32 e0 = pk[2 * st][0],     e1 = pk[2 * st][1];
                    u32 o0 = pk[2 * st + 1][0], o1 = pk[2 * st + 1][1];
                    u32 A0 = __shfl(e0, src0),      B0 = __shfl(o0, src0);
                    u32 A1 = __shfl(e1, src0),      B1 = __shfl(o1, src0);
                    u32 A2 = __shfl(e0, src0 + 16), B2 = __shfl(o0, src0 + 16);
                    u32 A3 = __shfl(e1, src0 + 16), B3 = __shfl(o1, src0 + 16);
                    u32 U0 = qhi ? B0 : A0;
                    u32 U1 = qhi ? B1 : A1;
                    u32 U2 = qhi ? B2 : A2;
                    u32 U3 = qhi ? B3 : A3;
                    bf16x8 pf = __builtin_bit_cast(bf16x8, make_uint4(U0, U1, U2, U3));
#pragma unroll
                    for (int dt = 0; dt < 4; ++dt) {
                        bf16x8 vf = ld_frag(&V[(dt * 16 + l15) * 64 +
                                               ((st * 4 + quad) ^ xsw) * 8]);
                        oacc[dt] = __builtin_amdgcn_mfma_f32_16x16x32_bf16(
                            vf, pf, oacc[dt], 0, 0, 0);
                    }
                }
            }
        }

        // epilogue: UNNORMALIZED partial O' (bf16), layout [bh][n][d]
#pragma unroll
        for (int dt = 0; dt < 4; ++dt) {
            ushort4 ov;
            ov.x = f2bf(oacc[dt][0]);
            ov.y = f2bf(oacc[dt][1]);
            ov.z = f2bf(oacc[dt][2]);
            ov.w = f2bf(oacc[dt][3]);
            *(ushort4*)&pb[((size_t)bh * Nn + qrow) * HD + dt * 16 + quad * 4] = ov;
        }
        if (quad == 0) {
            mb[bh * Nn + qrow] = m_i;
            lb[bh * Nn + qrow] = l_i;
        }
    }
}

// ---------------------------------------------------------------------------
// Merge: sa = (a1*p0 + a2*p1) / (a1*l1 + a2*l2), elementwise over [bh][n][d].
// Writes final sa IN PLACE over p1 (same layout, same index -> race-free).
// ---------------------------------------------------------------------------
__global__ __launch_bounds__(256) void attn_merge(
    const u16* __restrict__ p0, u16* __restrict__ p1,
    const float* __restrict__ ml)
{
    const int idx = blockIdx.x * 256 + threadIdx.x;  // 0..524287
    const int row = idx >> 3;                        // bh*2048+n
    const int dc = (idx & 7) * 8;

    const float m1 = ml[row],          l1 = ml[65536 + row];
    const float m2 = ml[131072 + row], l2 = ml[196608 + row];
    const float m = fmaxf(m1, m2);
    const float a1 = exp2f(m1 - m), a2 = exp2f(m2 - m);
    const float inv = 1.f / (a1 * l1 + a2 * l2);
    const float s1 = a1 * inv, s2 = a2 * inv;

    const size_t off = (size_t)row * HD + dc;
    uint4 v0 = *(const uint4*)&p0[off];
    uint4 v1 = *(const uint4*)&p1[off];
    u32 a[4] = {v0.x, v0.y, v0.z, v0.w};
    u32 b[4] = {v1.x, v1.y, v1.z, v1.w};
    u32 w[4];
#pragma unroll
    for (int j = 0; j < 4; ++j) {
        float x0 = bf2f((u16)a[j]) * s1 + bf2f((u16)b[j]) * s2;
        float x1 = bf2f((u16)(a[j] >> 16)) * s1 + bf2f((u16)(b[j] >> 16)) * s2;
        w[j] = pack2(x0, x1);
    }
    *(uint4*)&p1[off] = make_uint4(w[0], w[1], w[2], w[3]);
}

// ---------------------------------------------------------------------------
// Kernel 3: output projection, MFMA 32x32x16. A now in [bh][n][d] layout.
// ---------------------------------------------------------------------------
typedef float f32x16 __attribute__((ext_vector_type(16)));
__device__ __forceinline__ f32x16 zero16() {
    f32x16 z;
#pragma unroll
    for (int i = 0; i < 16; ++i) z[i] = 0.f;
    return z;
}

__global__ __launch_bounds__(256) void out_mfma(
    const u16* __restrict__ A, const u16* __restrict__ Wt,
    const float* __restrict__ bias, float* __restrict__ out)
{
    const int mt = blockIdx.x;  // 0..31
    const int nt = blockIdx.y;  // 0..15
    const int tid = threadIdx.x;
    const int lane = tid & 63, wid = tid >> 6;
    const int l31 = lane & 31, khalf = (lane >> 5) * 8;

    __shared__ u16 As[128][72];
    __shared__ u16 Bs[64][72];

    f32x16 acc[2];
    acc[0] = zero16(); acc[1] = zero16();

    const int arow = tid >> 1, akh = (tid & 1) * 32;
    const int gm = mt * 128 + arow;
    const int bb = gm >> 11, n = gm & (Nn - 1);
    const int brow = tid >> 2, bc = (tid & 3) * 16;

    for (int k0 = 0; k0 < Ee; k0 += 64) {
        __syncthreads();
        {
            // A element (gm, c=k0+akh+j): head h=c>>6, d=c&63; layout [b][h][n][d]
            const int c = k0 + akh;
            const int h = c >> 6, d0 = c & 63;
            const u16* asrc = A + (((size_t)(bb * Hh + h) * Nn + n) * HD + d0);
#pragma unroll
            for (int j = 0; j < 4; ++j)
                *(uint4*)&As[arow][akh + 8 * j] = *(const uint4*)(asrc + 8 * j);
            const u16* bsrc = Wt + (size_t)(nt * 64 + brow) * 1024 + k0 + bc;
            *(uint4*)&Bs[brow][bc]     = *(const uint4*)(bsrc);
            *(uint4*)&Bs[brow][bc + 8] = *(const uint4*)(bsrc + 8);
        }
        __syncthreads();
#pragma unroll
        for (int kc = 0; kc < 4; ++kc) {
            bf16x8 af = ld_frag(&As[wid * 32 + l31][kc * 16 + khalf]);
#pragma unroll
            for (int ct = 0; ct < 2; ++ct) {
                bf16x8 bf = ld_frag(&Bs[ct * 32 + l31][kc * 16 + khalf]);
                acc[ct] = __builtin_amdgcn_mfma_f32_32x32x16_bf16(af, bf, acc[ct], 0, 0, 0);
            }
        }
    }

#pragma unroll
    for (int ct = 0; ct < 2; ++ct) {
        int col = nt * 64 + ct * 32 + l31;
        float bv = bias[col];
#pragma unroll
        for (int r = 0; r < 16; ++r) {
            int row_l = (r & 3) + 8 * (r >> 2) + 4 * (lane >> 5);
            int gm2 = mt * 128 + wid * 32 + row_l;
            out[(size_t)gm2 * Ee + col] = acc[ct][r] + bv;
        }
    }
}

// ---------------------------------------------------------------------------
extern "C" void kernel_launch(void* const* d_in, const int* in_sizes, int n_in,
                              void* d_out, int out_size, void* d_ws, size_t ws_size,
                              hipStream_t stream) {
    const float* x    = (const float*)d_in[0];  // [2,2048,1024] f32
    const float* Wqkv = (const float*)d_in[1];  // [16,1024,192] f32
    const float* bqkv = (const float*)d_in[2];  // [16,192] f32
    const float* Wout = (const float*)d_in[3];  // [1024,1024] f32
    const float* bout = (const float*)d_in[4];  // [1024] f32
    float* out = (float*)d_out;                 // [2,2048,1024] f32

    const size_t SZ = (size_t)Bz * Hh * Nn * HD;        // 4,194,304 elems
    const size_t NSA = (size_t)Bz * Nn * Ee;            // 4,194,304 elems
    const size_t NEED = (3 * SZ + NSA) * sizeof(u16);   // 32 MiB

    if (ws_size < NEED) {
        ws_diag<<<1, 1, 0, stream>>>(out, 20000.0f + (float)(ws_size >> 20));
        return;
    }

    u16* ws = (u16*)d_ws;
    u16* kbuf  = ws;
    u16* qbuf  = ws + SZ;
    u16* vbuf  = ws + 2 * SZ;
    u16* sabuf = ws + 3 * SZ;
    u16* wqkv_t = sabuf;             // 6 MB (dead after qkv_mfma)
    u16* wout_t = kbuf;              // 2 MB (written after attn2)
    u16* xbf    = (u16*)d_out;       // 8 MB scratch (dead after qkv_mfma)
    u16* vtb    = (u16*)d_out + SZ;  // 8 MB scratch (dead after attn2)
    u16* p0     = (u16*)d_out;       // partial 0 (reuses xbf region)
    u16* p1     = vbuf;              // partial 1; merge writes final sa here
    float* ml   = (float*)sabuf;     // 4 x 64K f32 = 1 MB (m1,l1,m2,l2)

    convert_x<<<2048, 256, 0, stream>>>(x, xbf);
    transpose_f32_bf16<<<dim3(16, 3, 16), 256, 0, stream>>>(Wqkv, wqkv_t, 1024, 192);
    qkv_mfma<<<dim3(64, 16), 256, 0, stream>>>(xbf, wqkv_t, bqkv, kbuf, qbuf, vbuf);
    transpose_v<<<dim3(32, 32), 256, 0, stream>>>(vbuf, vtb);
    attn2<<<dim3(1024), 256, 0, stream>>>(qbuf, kbuf, vtb, p0, p1, ml);
    attn_merge<<<dim3(2048), 256, 0, stream>>>(p0, p1, ml);
    transpose_f32_bf16<<<dim3(16, 16, 1), 256, 0, stream>>>(Wout, wout_t, 1024, 1024);
    out_mfma<<<dim3(32, 16), 256, 0, stream>>>(p1, wout_t, bout, out);
}

// Round 12
// 196.914 us; speedup vs baseline: 1.0771x; 1.0431x over previous
//
#include <hip/hip_runtime.h>
#include <hip/hip_bf16.h>

// B=2, N=2048, E=1024, H=16, HD=64. Inputs fp32, output fp32.
// ws (32 MiB): kbuf qbuf vbuf sabuf (bf16, 8 MB each).
// Scratch plan:
//   wqkv_t (6 MB)  -> sabuf region, dead after qkv_mfma
//   xbf    (8 MB)  -> d_out[0..8M),  dead after qkv_mfma
//   vtb    (8 MB)  -> d_out[8..16M), dead after attn2
//   p0     (8 MB)  -> d_out[0..8M)  (attn2 partial 0, dead after merge)
//   p1     (8 MB)  -> vbuf          (partial 1; merge overwrites in place)
//   m/l    (1 MB)  -> sabuf head, dead after merge
//   wout_t (2 MB)  -> kbuf, written after attn2
// NOTE: Q is written PRE-SCALED by 0.125*log2(e) in qkv epilogue; attn2's
// softmax runs in the log2 domain with no per-element scale.
#define Bz 2
#define Nn 2048
#define Ee 1024
#define Hh 16
#define HD 64

typedef unsigned short u16;
typedef unsigned int u32;

typedef __bf16 bf16x8 __attribute__((ext_vector_type(8)));
typedef float f32x4 __attribute__((ext_vector_type(4)));

#define QK_SCALE 0.18033688f  // 0.125 * log2(e)

__device__ __forceinline__ float bf2f(u16 u) {
    u32 v = ((u32)u) << 16;
    return __builtin_bit_cast(float, v);
}
__device__ __forceinline__ u16 f2bf(float f) {
    u32 i = __builtin_bit_cast(u32, f);
    u32 r = (i + 0x7FFFu + ((i >> 16) & 1u)) >> 16;  // RNE
    return (u16)r;
}
__device__ __forceinline__ u32 pack2(float a, float b) {
    return (u32)f2bf(a) | ((u32)f2bf(b) << 16);
}
// cheap bf16 pair pack, round-half-up (for P in [0,1]; no overflow risk)
__device__ __forceinline__ u32 pack2h(float a, float b) {
    u32 ua = __builtin_bit_cast(u32, a) + 0x8000u;
    u32 ub = __builtin_bit_cast(u32, b) + 0x8000u;
    return (ua >> 16) | (ub & 0xFFFF0000u);
}
__device__ __forceinline__ bf16x8 ld_frag(const u16* p) {
    return __builtin_bit_cast(bf16x8, *(const uint4*)p);
}
__device__ __forceinline__ f32x4 zero4() {
    f32x4 z; z[0]=0.f; z[1]=0.f; z[2]=0.f; z[3]=0.f; return z;
}

// async 16B/lane global->LDS DMA; LDS dest = (uniform base) + lane*16.
__device__ __forceinline__ void async_copy16(const u16* g, u16* l) {
    __builtin_amdgcn_global_load_lds(
        (const __attribute__((address_space(1))) u32*)g,
        (__attribute__((address_space(3))) u32*)l, 16, 0, 0);
}

__global__ void ws_diag(float* out, float code) { out[0] = code; }

// ---------------------------------------------------------------------------
// x fp32 -> bf16 row-major into d_out scratch (first half).
// ---------------------------------------------------------------------------
__global__ __launch_bounds__(256) void convert_x(
    const float* __restrict__ x, u16* __restrict__ xbf)
{
    size_t idx = ((size_t)blockIdx.x * 256 + threadIdx.x) * 8;
    float4 f0 = *(const float4*)(x + idx);
    float4 f1 = *(const float4*)(x + idx + 4);
    uint4 pk;
    pk.x = pack2(f0.x, f0.y); pk.y = pack2(f0.z, f0.w);
    pk.z = pack2(f1.x, f1.y); pk.w = pack2(f1.z, f1.w);
    *(uint4*)(xbf + idx) = pk;
}

// ---------------------------------------------------------------------------
// Transpose f32 [R][C] -> bf16 [C][R], per z-slice.
// ---------------------------------------------------------------------------
__global__ __launch_bounds__(256) void transpose_f32_bf16(
    const float* __restrict__ src, u16* __restrict__ dst, int R, int C)
{
    const int r0 = blockIdx.x * 64, c0 = blockIdx.y * 64;
    const size_t zoff = (size_t)blockIdx.z * R * C;
    src += zoff; dst += zoff;
    const int tid = threadIdx.x;

    __shared__ float T[64][65];
    {
        int tr = tid >> 2, tc = (tid & 3) * 16;
        const float* s = src + (size_t)(r0 + tr) * C + c0 + tc;
#pragma unroll
        for (int j = 0; j < 4; ++j) {
            float4 v = ((const float4*)s)[j];
            T[tr][tc + 4 * j + 0] = v.x; T[tr][tc + 4 * j + 1] = v.y;
            T[tr][tc + 4 * j + 2] = v.z; T[tr][tc + 4 * j + 3] = v.w;
        }
    }
    __syncthreads();
    {
        int cc = tid >> 2, rr = (tid & 3) * 16;
        u16* d = dst + (size_t)(c0 + cc) * R + r0 + rr;
        u32 w[8];
#pragma unroll
        for (int i = 0; i < 8; ++i)
            w[i] = pack2(T[rr + 2 * i][cc], T[rr + 2 * i + 1][cc]);
        *(uint4*)(d)     = make_uint4(w[0], w[1], w[2], w[3]);
        *(uint4*)(d + 8) = make_uint4(w[4], w[5], w[6], w[7]);
    }
}

// ---------------------------------------------------------------------------
// Transpose bf16 [2048 n][64 d] -> [64 d][2048 n] per bh slice (V -> V^T).
// ---------------------------------------------------------------------------
__global__ __launch_bounds__(256) void transpose_v(
    const u16* __restrict__ src, u16* __restrict__ dst)
{
    const int n0 = blockIdx.x * 64;
    const size_t z = blockIdx.y;
    src += z * (size_t)Nn * HD;
    dst += z * (size_t)HD * Nn;
    const int tid = threadIdx.x;

    __shared__ u16 T[64][66];
    {
        int tr = tid >> 2, tc = (tid & 3) * 16;
        const u16* s = src + (size_t)(n0 + tr) * HD + tc;
        *(uint4*)&T[tr][tc]     = *(const uint4*)(s);
        *(uint4*)&T[tr][tc + 8] = *(const uint4*)(s + 8);
    }
    __syncthreads();
    {
        int cc = tid >> 2, rr = (tid & 3) * 16;
        u32 w[8];
#pragma unroll
        for (int i = 0; i < 8; ++i)
            w[i] = (u32)T[rr + 2 * i][cc] | ((u32)T[rr + 2 * i + 1][cc] << 16);
        u16* d = dst + (size_t)cc * Nn + n0 + rr;
        *(uint4*)(d)     = make_uint4(w[0], w[1], w[2], w[3]);
        *(uint4*)(d + 8) = make_uint4(w[4], w[5], w[6], w[7]);
    }
}

// ---------------------------------------------------------------------------
// Kernel 1 v3: QKV projection, MFMA 16x16x32, async staging.
// Block 128m x 192n (one head), grid (32,16)=512. 4 waves 2x2, wave 64x96
// (4x6 frags -> 48 MFMA per k64 iter). LDS 40 KB unpadded, XOR chunk swizzle.
// Q output pre-scaled by QK_SCALE.
// ---------------------------------------------------------------------------
__global__ __launch_bounds__(256) void qkv_mfma(
    const u16* __restrict__ xbf, const u16* __restrict__ Wt,
    const float* __restrict__ bias,
    u16* __restrict__ kbuf, u16* __restrict__ qbuf, u16* __restrict__ vbuf)
{
    const int mt = blockIdx.x;   // 0..31
    const int h  = blockIdx.y;   // 0..15
    const int tid = threadIdx.x;
    const int lane = tid & 63, wid = tid >> 6;
    const int wy = wid >> 1, wx = wid & 1;
    const int quad = lane >> 4, l15 = lane & 15;

    __shared__ u16 As[128 * 64];   // [m][8 chunks of 8], swizzled
    __shared__ u16 Bs[192 * 64];   // [n][8 chunks], swizzled

    f32x4 acc[4][6];
#pragma unroll
    for (int mi = 0; mi < 4; ++mi)
#pragma unroll
        for (int ni = 0; ni < 6; ++ni) acc[mi][ni] = zero4();

    const u16* xb = xbf + (size_t)mt * 128 * Ee;
    const u16* wtb = Wt + (size_t)h * 192 * 1024;

    const int arowl = lane >> 3;
    const int jj = (lane & 7) ^ arowl;

    for (int kb = 0; kb < 16; ++kb) {
        __syncthreads();  // prev-iter frag reads done
        // A: 128x64 = 16 KB = 16 insts, 4 per wave
#pragma unroll
        for (int i = 0; i < 4; ++i) {
            int rbase = (wid * 4 + i) * 8;
            const u16* g = xb + (size_t)(rbase + arowl) * Ee + kb * 64 + jj * 8;
            async_copy16(g, &As[(wid * 4 + i) * 512]);
        }
        // B: 192x64 = 24 KB = 24 insts, 6 per wave
#pragma unroll
        for (int i = 0; i < 6; ++i) {
            int rbase = (wid * 6 + i) * 8;
            const u16* g = wtb + (size_t)(rbase + arowl) * 1024 + kb * 64 + jj * 8;
            async_copy16(g, &Bs[(wid * 6 + i) * 512]);
        }
        __syncthreads();  // drains vmcnt before barrier

#pragma unroll
        for (int kk0 = 0; kk0 < 2; ++kk0) {
            const int pos = ((kk0 * 4 + quad) ^ (l15 & 7)) * 8;
            bf16x8 af[4], bf[6];
#pragma unroll
            for (int mi = 0; mi < 4; ++mi)
                af[mi] = ld_frag(&As[(wy * 64 + mi * 16 + l15) * 64 + pos]);
#pragma unroll
            for (int ni = 0; ni < 6; ++ni)
                bf[ni] = ld_frag(&Bs[(wx * 96 + ni * 16 + l15) * 64 + pos]);
#pragma unroll
            for (int mi = 0; mi < 4; ++mi)
#pragma unroll
                for (int ni = 0; ni < 6; ++ni)
                    acc[mi][ni] = __builtin_amdgcn_mfma_f32_16x16x32_bf16(
                        af[mi], bf[ni], acc[mi][ni], 0, 0, 0);
        }
    }

    // epilogue: C layout col=l15, row=quad*4+r. cols 0..191 = k|q|v.
    // Q (ft==1) is pre-scaled by QK_SCALE.
#pragma unroll
    for (int ni = 0; ni < 6; ++ni) {
        int col = wx * 96 + ni * 16 + l15;   // 0..191
        int ft = col >> 6, d = col & 63;
        u16* dst = (ft == 0) ? kbuf : (ft == 1) ? qbuf : vbuf;
        float sc = (ft == 1) ? QK_SCALE : 1.0f;
        float bv = bias[h * 192 + col];
#pragma unroll
        for (int mi = 0; mi < 4; ++mi)
#pragma unroll
            for (int r = 0; r < 4; ++r) {
                int gm = mt * 128 + wy * 64 + mi * 16 + quad * 4 + r;
                int bb = gm >> 11, n = gm & (Nn - 1);
                dst[(((size_t)(bb * Hh + h)) * Nn + n) * HD + d] =
                    f2bf((acc[mi][ni][r] + bv) * sc);
            }
    }
}

// ---------------------------------------------------------------------------
// Kernel 2 v6: split-K causal flash attention, transposed-S, MFMA 16x16x32.
// As R11, minus per-element scaling (Q pre-scaled) and with cheap P packing.
// ---------------------------------------------------------------------------
__global__ __launch_bounds__(256) void attn2(
    const u16* __restrict__ qbuf, const u16* __restrict__ kbuf,
    const u16* __restrict__ vtb, u16* __restrict__ p0buf,
    u16* __restrict__ p1buf, float* __restrict__ ml)
{
    const int id = blockIdx.x;                      // 0..1023
    const int bh = (id & 7) * 4 + ((id >> 3) & 3);  // 4 bh per XCD
    const int p  = id >> 5;                         // 0..31
    const int tid = threadIdx.x;
    const int lane = tid & 63, wid = tid >> 6;
    const int l15 = lane & 15, quad = lane >> 4;

    __shared__ u16 KsL[2][4096];   // [buf][key 64][d 64] chunk-swizzled
    __shared__ u16 VtL[2][4096];   // [buf][d 64][key 64] chunk-swizzled

    const u16* qb = qbuf + (size_t)bh * Nn * HD;
    const u16* kb = kbuf + (size_t)bh * Nn * HD;
    const u16* vt = vtb + (size_t)bh * HD * Nn;

    const int r_l = lane >> 3;
    const int jj = (lane & 7) ^ r_l;
    const int xsw = l15 & 7;
    const int src0 = l15 + (quad & 1) * 32;
    const bool qhi = quad >= 2;

    for (int sg = 0; sg < 2; ++sg) {
        const int qt = sg ? (31 - p) : p;
        const int T  = qt + 1;
        const int t0 = sg ? ((T + 1) >> 1) : 0;
        const int t1 = sg ? T : ((p + 2) >> 1);
        u16*   pb = sg ? p1buf : p0buf;
        float* mb = ml + (sg ? 131072 : 0);
        float* lb = ml + (sg ? 196608 : 65536);

        const int qrow = qt * 64 + wid * 16 + l15;

        f32x4 oacc[4];
#pragma unroll
        for (int dt = 0; dt < 4; ++dt) oacc[dt] = zero4();
        float m_i = -3e38f, l_i = 0.f;

        if (t0 < t1) {
            bf16x8 qf[2];
#pragma unroll
            for (int st = 0; st < 2; ++st)
                qf[st] = __builtin_bit_cast(bf16x8,
                    *(const uint4*)(qb + (size_t)qrow * HD + st * 32 + quad * 8));

            __syncthreads();
#pragma unroll
            for (int i2 = 0; i2 < 4; ++i2) {
                int idx = wid * 4 + i2;
                if (idx < 8) {
                    const u16* g = kb + (size_t)(t0 * 64 + idx * 8 + r_l) * HD + jj * 8;
                    async_copy16(g, &KsL[0][idx * 512]);
                } else {
                    int ii = idx - 8;
                    const u16* g = vt + (size_t)(ii * 8 + r_l) * Nn + t0 * 64 + jj * 8;
                    async_copy16(g, &VtL[0][ii * 512]);
                }
            }

            const int nit = t1 - t0;
            for (int i = 0; i < nit; ++i) {
                const int tk = t0 + i;
                __syncthreads();  // drains DMA for buf[i&1]; fences prev reads
                if (i + 1 < nit) {
                    const int nb = (i + 1) & 1;
#pragma unroll
                    for (int i2 = 0; i2 < 4; ++i2) {
                        int idx = wid * 4 + i2;
                        if (idx < 8) {
                            const u16* g = kb + (size_t)((tk + 1) * 64 + idx * 8 + r_l) * HD + jj * 8;
                            async_copy16(g, &KsL[nb][idx * 512]);
                        } else {
                            int ii = idx - 8;
                            const u16* g = vt + (size_t)(ii * 8 + r_l) * Nn + (tk + 1) * 64 + jj * 8;
                            async_copy16(g, &VtL[nb][ii * 512]);
                        }
                    }
                }
                const u16* K = KsL[i & 1];
                const u16* V = VtL[i & 1];

                // S^T[key][q] (already log2-scaled via Q)
                f32x4 s[4];
#pragma unroll
                for (int t = 0; t < 4; ++t) {
                    f32x4 a = zero4();
#pragma unroll
                    for (int st = 0; st < 2; ++st) {
                        bf16x8 kf = ld_frag(&K[(t * 16 + l15) * 64 +
                                               ((st * 4 + quad) ^ xsw) * 8]);
                        a = __builtin_amdgcn_mfma_f32_16x16x32_bf16(kf, qf[st], a, 0, 0, 0);
                    }
                    s[t] = a;
                }

                // causal mask only on the diagonal tile
                if (tk == qt) {
#pragma unroll
                    for (int t = 0; t < 4; ++t)
#pragma unroll
                        for (int r = 0; r < 4; ++r) {
                            int key = tk * 64 + t * 16 + quad * 4 + r;
                            if (key > qrow) s[t][r] = -3e38f;
                        }
                }

                // online softmax: in-lane + 2 shuffles; exp2
                float mx = s[0][0];
#pragma unroll
                for (int t = 0; t < 4; ++t)
#pragma unroll
                    for (int r = 0; r < 4; ++r) mx = fmaxf(mx, s[t][r]);
                mx = fmaxf(mx, __shfl_xor(mx, 16));
                mx = fmaxf(mx, __shfl_xor(mx, 32));
                float mn = fmaxf(m_i, mx);
                float alpha = exp2f(m_i - mn);
                m_i = mn;
                float rs = 0.f;
#pragma unroll
                for (int t = 0; t < 4; ++t)
#pragma unroll
                    for (int r = 0; r < 4; ++r) {
                        float e = exp2f(s[t][r] - mn);
                        s[t][r] = e;
                        rs += e;
                    }
                rs += __shfl_xor(rs, 16);
                rs += __shfl_xor(rs, 32);
                l_i = l_i * alpha + rs;
#pragma unroll
                for (int dt = 0; dt < 4; ++dt)
#pragma unroll
                    for (int r = 0; r < 4; ++r) oacc[dt][r] *= alpha;

                // pack P (round-half-up); B-frags via both-candidate shuffle
                u32 pk[4][2];
#pragma unroll
                for (int t = 0; t < 4; ++t) {
                    pk[t][0] = pack2h(s[t][0], s[t][1]);
                    pk[t][1] = pack2h(s[t][2], s[t][3]);
                }
#pragma unroll
                for (int st = 0; st < 2; ++st) {
                    u32 e0 = pk[2 * st][0],     e1 = pk[2 * st][1];
                    u32 o0 = pk[2 * st + 1][0], o1 = pk[2 * st + 1][1];
                    u32 A0 = __shfl(e0, src0),      B0 = __shfl(o0, src0);
                    u32 A1 = __shfl(e1, src0),      B1 = __shfl(o1, src0);
                    u32 A2 = __shfl(e0, src0 + 16), B2 = __shfl(o0, src0 + 16);
                    u32 A3 = __shfl(e1, src0 + 16), B3 = __shfl(o1, src0 + 16);
                    u32 U0 = qhi ? B0 : A0;
                    u32 U1 = qhi ? B1 : A1;
                    u32 U2 = qhi ? B2 : A2;
                    u32 U3 = qhi ? B3 : A3;
                    bf16x8 pf = __builtin_bit_cast(bf16x8, make_uint4(U0, U1, U2, U3));
#pragma unroll
                    for (int dt = 0; dt < 4; ++dt) {
                        bf16x8 vf = ld_frag(&V[(dt * 16 + l15) * 64 +
                                               ((st * 4 + quad) ^ xsw) * 8]);
                        oacc[dt] = __builtin_amdgcn_mfma_f32_16x16x32_bf16(
                            vf, pf, oacc[dt], 0, 0, 0);
                    }
                }
            }
        }

        // epilogue: UNNORMALIZED partial O' (bf16), layout [bh][n][d]
#pragma unroll
        for (int dt = 0; dt < 4; ++dt) {
            ushort4 ov;
            ov.x = f2bf(oacc[dt][0]);
            ov.y = f2bf(oacc[dt][1]);
            ov.z = f2bf(oacc[dt][2]);
            ov.w = f2bf(oacc[dt][3]);
            *(ushort4*)&pb[((size_t)bh * Nn + qrow) * HD + dt * 16 + quad * 4] = ov;
        }
        if (quad == 0) {
            mb[bh * Nn + qrow] = m_i;
            lb[bh * Nn + qrow] = l_i;
        }
    }
}

// ---------------------------------------------------------------------------
// Merge: sa = (a1*p0 + a2*p1) / (a1*l1 + a2*l2); writes in place over p1.
// ---------------------------------------------------------------------------
__global__ __launch_bounds__(256) void attn_merge(
    const u16* __restrict__ p0, u16* __restrict__ p1,
    const float* __restrict__ ml)
{
    const int idx = blockIdx.x * 256 + threadIdx.x;  // 0..524287
    const int row = idx >> 3;                        // bh*2048+n
    const int dc = (idx & 7) * 8;

    const float m1 = ml[row],          l1 = ml[65536 + row];
    const float m2 = ml[131072 + row], l2 = ml[196608 + row];
    const float m = fmaxf(m1, m2);
    const float a1 = exp2f(m1 - m), a2 = exp2f(m2 - m);
    const float inv = 1.f / (a1 * l1 + a2 * l2);
    const float s1 = a1 * inv, s2 = a2 * inv;

    const size_t off = (size_t)row * HD + dc;
    uint4 v0 = *(const uint4*)&p0[off];
    uint4 v1 = *(const uint4*)&p1[off];
    u32 a[4] = {v0.x, v0.y, v0.z, v0.w};
    u32 b[4] = {v1.x, v1.y, v1.z, v1.w};
    u32 w[4];
#pragma unroll
    for (int j = 0; j < 4; ++j) {
        float x0 = bf2f((u16)a[j]) * s1 + bf2f((u16)b[j]) * s2;
        float x1 = bf2f((u16)(a[j] >> 16)) * s1 + bf2f((u16)(b[j] >> 16)) * s2;
        w[j] = pack2(x0, x1);
    }
    *(uint4*)&p1[off] = make_uint4(w[0], w[1], w[2], w[3]);
}

// ---------------------------------------------------------------------------
// Kernel 3: output projection, MFMA 32x32x16. A in [bh][n][d] layout.
// ---------------------------------------------------------------------------
typedef float f32x16 __attribute__((ext_vector_type(16)));
__device__ __forceinline__ f32x16 zero16() {
    f32x16 z;
#pragma unroll
    for (int i = 0; i < 16; ++i) z[i] = 0.f;
    return z;
}

__global__ __launch_bounds__(256) void out_mfma(
    const u16* __restrict__ A, const u16* __restrict__ Wt,
    const float* __restrict__ bias, float* __restrict__ out)
{
    const int mt = blockIdx.x;  // 0..31
    const int nt = blockIdx.y;  // 0..15
    const int tid = threadIdx.x;
    const int lane = tid & 63, wid = tid >> 6;
    const int l31 = lane & 31, khalf = (lane >> 5) * 8;

    __shared__ u16 As[128][72];
    __shared__ u16 Bs[64][72];

    f32x16 acc[2];
    acc[0] = zero16(); acc[1] = zero16();

    const int arow = tid >> 1, akh = (tid & 1) * 32;
    const int gm = mt * 128 + arow;
    const int bb = gm >> 11, n = gm & (Nn - 1);
    const int brow = tid >> 2, bc = (tid & 3) * 16;

    for (int k0 = 0; k0 < Ee; k0 += 64) {
        __syncthreads();
        {
            const int c = k0 + akh;
            const int h = c >> 6, d0 = c & 63;
            const u16* asrc = A + (((size_t)(bb * Hh + h) * Nn + n) * HD + d0);
#pragma unroll
            for (int j = 0; j < 4; ++j)
                *(uint4*)&As[arow][akh + 8 * j] = *(const uint4*)(asrc + 8 * j);
            const u16* bsrc = Wt + (size_t)(nt * 64 + brow) * 1024 + k0 + bc;
            *(uint4*)&Bs[brow][bc]     = *(const uint4*)(bsrc);
            *(uint4*)&Bs[brow][bc + 8] = *(const uint4*)(bsrc + 8);
        }
        __syncthreads();
#pragma unroll
        for (int kc = 0; kc < 4; ++kc) {
            bf16x8 af = ld_frag(&As[wid * 32 + l31][kc * 16 + khalf]);
#pragma unroll
            for (int ct = 0; ct < 2; ++ct) {
                bf16x8 bf = ld_frag(&Bs[ct * 32 + l31][kc * 16 + khalf]);
                acc[ct] = __builtin_amdgcn_mfma_f32_32x32x16_bf16(af, bf, acc[ct], 0, 0, 0);
            }
        }
    }

#pragma unroll
    for (int ct = 0; ct < 2; ++ct) {
        int col = nt * 64 + ct * 32 + l31;
        float bv = bias[col];
#pragma unroll
        for (int r = 0; r < 16; ++r) {
            int row_l = (r & 3) + 8 * (r >> 2) + 4 * (lane >> 5);
            int gm2 = mt * 128 + wid * 32 + row_l;
            out[(size_t)gm2 * Ee + col] = acc[ct][r] + bv;
        }
    }
}

// ---------------------------------------------------------------------------
extern "C" void kernel_launch(void* const* d_in, const int* in_sizes, int n_in,
                              void* d_out, int out_size, void* d_ws, size_t ws_size,
                              hipStream_t stream) {
    const float* x    = (const float*)d_in[0];  // [2,2048,1024] f32
    const float* Wqkv = (const float*)d_in[1];  // [16,1024,192] f32
    const float* bqkv = (const float*)d_in[2];  // [16,192] f32
    const float* Wout = (const float*)d_in[3];  // [1024,1024] f32
    const float* bout = (const float*)d_in[4];  // [1024] f32
    float* out = (float*)d_out;                 // [2,2048,1024] f32

    const size_t SZ = (size_t)Bz * Hh * Nn * HD;        // 4,194,304 elems
    const size_t NSA = (size_t)Bz * Nn * Ee;            // 4,194,304 elems
    const size_t NEED = (3 * SZ + NSA) * sizeof(u16);   // 32 MiB

    if (ws_size < NEED) {
        ws_diag<<<1, 1, 0, stream>>>(out, 20000.0f + (float)(ws_size >> 20));
        return;
    }

    u16* ws = (u16*)d_ws;
    u16* kbuf  = ws;
    u16* qbuf  = ws + SZ;
    u16* vbuf  = ws + 2 * SZ;
    u16* sabuf = ws + 3 * SZ;
    u16* wqkv_t = sabuf;             // 6 MB (dead after qkv_mfma)
    u16* wout_t = kbuf;              // 2 MB (written after attn2)
    u16* xbf    = (u16*)d_out;       // 8 MB scratch (dead after qkv_mfma)
    u16* vtb    = (u16*)d_out + SZ;  // 8 MB scratch (dead after attn2)
    u16* p0     = (u16*)d_out;       // partial 0 (reuses xbf region)
    u16* p1     = vbuf;              // partial 1; merge writes final sa here
    float* ml   = (float*)sabuf;     // 4 x 64K f32 = 1 MB

    convert_x<<<2048, 256, 0, stream>>>(x, xbf);
    transpose_f32_bf16<<<dim3(16, 3, 16), 256, 0, stream>>>(Wqkv, wqkv_t, 1024, 192);
    qkv_mfma<<<dim3(32, 16), 256, 0, stream>>>(xbf, wqkv_t, bqkv, kbuf, qbuf, vbuf);
    transpose_v<<<dim3(32, 32), 256, 0, stream>>>(vbuf, vtb);
    attn2<<<dim3(1024), 256, 0, stream>>>(qbuf, kbuf, vtb, p0, p1, ml);
    attn_merge<<<dim3(2048), 256, 0, stream>>>(p0, p1, ml);
    transpose_f32_bf16<<<dim3(16, 16, 1), 256, 0, stream>>>(Wout, wout_t, 1024, 1024);
    out_mfma<<<dim3(32, 16), 256, 0, stream>>>(p1, wout_t, bout, out);
}